// Round 1
// baseline (981.862 us; speedup 1.0000x reference)
//
#include <hip/hip_runtime.h>

#define N 4096
#define IN_DIM 256
#define HID 64
#define NHEADS 4
#define OUT_DIM 128
#define JSPLIT 16
#define CHUNK (N / JSPLIT) /* 256 */

// ---------------------------------------------------------------------------
// gemm1: x[N,256] @ W_heads[4][256][64] -> Wh1[4][N][64]
// block 256 thr: h = t>>6, c = t&63; 8 rows/block; grid = N/8 = 512
// ---------------------------------------------------------------------------
__global__ void gemm1_kernel(const float* __restrict__ x,
                             const float* __restrict__ W,
                             float* __restrict__ Wh) {
    __shared__ float xs[8 * IN_DIM];
    const int t = threadIdx.x;
    const int c = t & 63, h = t >> 6;
    const int i0 = blockIdx.x * 8;
    const float4* xg = (const float4*)(x + (size_t)i0 * IN_DIM);
    float4* xs4 = (float4*)xs;
    for (int u = t; u < 8 * IN_DIM / 4; u += 256) xs4[u] = xg[u];
    __syncthreads();
    float acc[8];
#pragma unroll
    for (int r = 0; r < 8; r++) acc[r] = 0.f;
    const float* Wp = W + (size_t)h * IN_DIM * HID + c;
    for (int k = 0; k < IN_DIM; k += 4) {
        const float w0 = Wp[(size_t)(k + 0) * HID];
        const float w1 = Wp[(size_t)(k + 1) * HID];
        const float w2 = Wp[(size_t)(k + 2) * HID];
        const float w3 = Wp[(size_t)(k + 3) * HID];
#pragma unroll
        for (int r = 0; r < 8; r++) {
            const float4 xv = *(const float4*)(xs + r * IN_DIM + k);
            acc[r] += xv.x * w0 + xv.y * w1 + xv.z * w2 + xv.w * w3;
        }
    }
#pragma unroll
    for (int r = 0; r < 8; r++)
        Wh[((size_t)h * N + (i0 + r)) * HID + c] = acc[r];
}

// ---------------------------------------------------------------------------
// fkern1: f1[h][i] = sum_c Wh[h][i][c]*a[h][c]; f2 with a[h][64+c]
// grid N blocks x 256 thr (wave = head)
// ---------------------------------------------------------------------------
__global__ void fkern1(const float* __restrict__ Wh, const float* __restrict__ a,
                       float* __restrict__ f1, float* __restrict__ f2) {
    const int i = blockIdx.x;
    const int t = threadIdx.x;
    const int h = t >> 6, c = t & 63;
    const float v = Wh[((size_t)h * N + i) * HID + c];
    float v1 = v * a[h * 2 * HID + c];
    float v2 = v * a[h * 2 * HID + HID + c];
#pragma unroll
    for (int m = 32; m > 0; m >>= 1) {
        v1 += __shfl_xor(v1, m, 64);
        v2 += __shfl_xor(v2, m, 64);
    }
    if (c == 0) { f1[(size_t)h * N + i] = v1; f2[(size_t)h * N + i] = v2; }
}

// ---------------------------------------------------------------------------
// fkern2: f1b[i] = sum_c Wh2[i][c]*a_out[c]; f2b with a_out[128+c]
// grid N blocks x 128 thr (2 waves)
// ---------------------------------------------------------------------------
__global__ void fkern2(const float* __restrict__ Wh2, const float* __restrict__ a2,
                       float* __restrict__ f1, float* __restrict__ f2) {
    __shared__ float red[4];
    const int i = blockIdx.x, t = threadIdx.x;
    const float v = Wh2[(size_t)i * OUT_DIM + t];
    float v1 = v * a2[t];
    float v2 = v * a2[OUT_DIM + t];
#pragma unroll
    for (int m = 32; m > 0; m >>= 1) {
        v1 += __shfl_xor(v1, m, 64);
        v2 += __shfl_xor(v2, m, 64);
    }
    const int w = t >> 6;
    if ((t & 63) == 0) { red[w * 2] = v1; red[w * 2 + 1] = v2; }
    __syncthreads();
    if (t == 0) { f1[i] = red[0] + red[2]; f2[i] = red[1] + red[3]; }
}

// ---------------------------------------------------------------------------
// Fused single-pass masked-softmax aggregation (no max subtraction needed:
// |f1+f2| is O(1), exp cannot overflow; masked lanes contribute exactly 0,
// matching exp(-9e15)=0 in the reference).
// Thread owns (head h, colslice cs, row r): acc[DSUB] in VGPRs.
// grid: (N/64 row blocks, JSPLIT j-chunks). Partials to workspace.
// Layer1: NH=4, DSUB=64, NCS=1, D=64,  OUTW=256
// Layer2: NH=1, DSUB=32, NCS=4, D=128, OUTW=128
// ---------------------------------------------------------------------------
template <int NH, int DSUB, int NCS, int D, int OUTW>
__global__ __launch_bounds__(256, 4) void attn_kernel(
        const int* __restrict__ adj, const float* __restrict__ Wh,
        const float* __restrict__ f1g, const float* __restrict__ f2g,
        float* __restrict__ partA, float* __restrict__ partS) {
    const int t = threadIdx.x;
    const int slot = t >> 6, r = t & 63;
    const int h = slot / NCS, cs = slot % NCS;
    const int c0 = cs * DSUB;
    const int i = blockIdx.x * 64 + r;
    const int split = blockIdx.y;
    const int j0 = split * CHUNK;

    const float f1 = f1g[(size_t)h * N + i];
    const int* adjp = adj + (size_t)i * N + j0;
    const float* f2p = f2g + (size_t)h * N + j0;
    const float* whp = Wh + ((size_t)h * N + j0) * D + c0;

    float acc[DSUB];
#pragma unroll
    for (int q = 0; q < DSUB; q++) acc[q] = 0.f;
    float s = 0.f;

    for (int jj = 0; jj < CHUNK; jj += 4) {
        const int4 a4 = *(const int4*)(adjp + jj);
        const float4 f4 = *(const float4*)(f2p + jj);
        const int am[4] = {a4.x, a4.y, a4.z, a4.w};
        const float fm[4] = {f4.x, f4.y, f4.z, f4.w};
#pragma unroll
        for (int u = 0; u < 4; u++) {
            float e = f1 + fm[u];
            e = fmaxf(e, 0.5f * e);              // LeakyReLU(0.5), monotone
            const float p = (am[u] > 0) ? __expf(e) : 0.f;
            s += p;
            const float4* wp = (const float4*)(whp + (size_t)(jj + u) * D);
#pragma unroll
            for (int q = 0; q < DSUB / 4; q++) {
                const float4 w = wp[q];
                acc[4 * q + 0] += p * w.x;
                acc[4 * q + 1] += p * w.y;
                acc[4 * q + 2] += p * w.z;
                acc[4 * q + 3] += p * w.w;
            }
        }
    }

    // partA[(split*OUTW + slot*DSUB + q)][i]  (column-major in i: coalesced)
#pragma unroll
    for (int q = 0; q < DSUB; q++)
        partA[((size_t)split * OUTW + slot * DSUB + q) * N + i] = acc[q];
    if (cs == 0) partS[((size_t)split * NH + h) * N + i] = s;
}

// ---------------------------------------------------------------------------
// reduce: combine j-split partials, divide by softmax denom, apply ELU.
// grid (N/256, OUTW); layer1 writes h1T[hc][i] (transposed), layer2 writes
// out[i][hc].
// ---------------------------------------------------------------------------
__global__ void reduce_kernel(const float* __restrict__ partA,
                              const float* __restrict__ partS,
                              float* __restrict__ outp, int OUTW, int NH,
                              int strideC, int strideI) {
    const int i = blockIdx.x * 256 + threadIdx.x;
    const int hc = blockIdx.y;
    const int hd = hc / (OUTW / NH);
    float a = 0.f, ss = 0.f;
    for (int sp = 0; sp < JSPLIT; sp++) {
        a  += partA[((size_t)sp * OUTW + hc) * N + i];
        ss += partS[((size_t)sp * NH + hd) * N + i];
    }
    float v = a / ss;
    v = (v > 0.f) ? v : (__expf(v) - 1.f);       // ELU
    outp[(size_t)hc * strideC + (size_t)i * strideI] = v;
}

// ---------------------------------------------------------------------------
// gemm2: h1T[256][N] (k-major) @ W_out[256][128] -> Wh2[N][128]
// block 256 thr: c = t&127, rh = t>>7; 8 rows/block; grid = N/8
// ---------------------------------------------------------------------------
__global__ void gemm2_kernel(const float* __restrict__ h1T,
                             const float* __restrict__ W2,
                             float* __restrict__ Wh2) {
    __shared__ float hs[8 * IN_DIM];
    const int t = threadIdx.x;
    const int c = t & 127, rh = t >> 7;
    const int i0 = blockIdx.x * 8;
    for (int u = t; u < 8 * IN_DIM; u += 256) {
        const int r = u & 7, k = u >> 3;
        hs[r * IN_DIM + k] = h1T[(size_t)k * N + i0 + r];
    }
    __syncthreads();
    float acc[4];
#pragma unroll
    for (int rr = 0; rr < 4; rr++) acc[rr] = 0.f;
    for (int k = 0; k < IN_DIM; k += 4) {
        const float w0 = W2[(size_t)(k + 0) * OUT_DIM + c];
        const float w1 = W2[(size_t)(k + 1) * OUT_DIM + c];
        const float w2 = W2[(size_t)(k + 2) * OUT_DIM + c];
        const float w3 = W2[(size_t)(k + 3) * OUT_DIM + c];
#pragma unroll
        for (int rr = 0; rr < 4; rr++) {
            const float4 hv = *(const float4*)(hs + (rh * 4 + rr) * IN_DIM + k);
            acc[rr] += hv.x * w0 + hv.y * w1 + hv.z * w2 + hv.w * w3;
        }
    }
#pragma unroll
    for (int rr = 0; rr < 4; rr++)
        Wh2[(size_t)(i0 + rh * 4 + rr) * OUT_DIM + c] = acc[rr];
}

// ---------------------------------------------------------------------------
extern "C" void kernel_launch(void* const* d_in, const int* in_sizes, int n_in,
                              void* d_out, int out_size, void* d_ws, size_t ws_size,
                              hipStream_t stream) {
    const float* x   = (const float*)d_in[0];
    const int*   adj = (const int*)d_in[1];
    const float* Wh_ = (const float*)d_in[2];
    const float* ah  = (const float*)d_in[3];
    const float* W2  = (const float*)d_in[4];
    const float* a2  = (const float*)d_in[5];
    float* out = (float*)d_out;

    float* ws   = (float*)d_ws;
    float* Wh1  = ws;                                  // 4*N*64   = 1048576
    float* f1a  = Wh1 + (size_t)NHEADS * N * HID;      // 16384
    float* f2a  = f1a + (size_t)NHEADS * N;            // 16384
    float* h1T  = f2a + (size_t)NHEADS * N;            // 256*N    = 1048576
    float* Wh2v = h1T + (size_t)IN_DIM * N;            // N*128    = 524288
    float* f1b  = Wh2v + (size_t)N * OUT_DIM;          // 4096
    float* f2b  = f1b + N;                             // 4096
    float* partA = f2b + N;                            // 16*256*N = 16777216
    float* partS = partA + (size_t)JSPLIT * 256 * N;   // 16*4*N   = 262144

    // ---- layer 1 ----
    gemm1_kernel<<<N / 8, 256, 0, stream>>>(x, Wh_, Wh1);
    fkern1<<<N, 256, 0, stream>>>(Wh1, ah, f1a, f2a);
    attn_kernel<NHEADS, 64, 1, 64, 256>
        <<<dim3(N / 64, JSPLIT), 256, 0, stream>>>(adj, Wh1, f1a, f2a, partA, partS);
    reduce_kernel<<<dim3(N / 256, 256), 256, 0, stream>>>(
        partA, partS, h1T, 256, NHEADS, N, 1);

    // ---- layer 2 ----
    gemm2_kernel<<<N / 8, 256, 0, stream>>>(h1T, W2, Wh2v);
    fkern2<<<N, 128, 0, stream>>>(Wh2v, a2, f1b, f2b);
    attn_kernel<1, 32, 4, 128, 128>
        <<<dim3(N / 64, JSPLIT), 256, 0, stream>>>(adj, Wh2v, f1b, f2b, partA, partS);
    reduce_kernel<<<dim3(N / 256, 128), 256, 0, stream>>>(
        partA, partS, out, 128, 1, 1, 128);
}